// Round 5
// baseline (262.877 us; speedup 1.0000x reference)
//
#include <hip/hip_runtime.h>
#include <math.h>

#define B_ 4
#define H_ 192
#define W_ 192
#define Q_ 160
#define E_ 96
#define M_ 96
#define HW_ (H_ * W_)          // 36864
#define NPIX_ (B_ * HW_)       // 147456
#define NTILE 9                // wave-tiles per block: 36864/(256 slots*16 px), 4 px/wave
#define WTILE_B 4096           // per-wave tile: 4*(640+384) bytes
#define NDICE 1024             // 256 slots per batch * 4 batches
#define NSMALL 962             // 2 + 384 + 576
#define NBUCKET 64
// ws layout (floats): [0]=class [1]=bce [2]=nll [3]=occ
//   [4   + k*4 + b] k<64 : dice numerator partials
//   [260 + k*4 + b] k<64 : sum_true partials
#define WS_NUM0 4
#define WS_TS0  260
#define WS_TOTAL 516

// ---- async global->LDS, 16 B per lane; lds dest = wave-uniform base + lane*16;
//      global SOURCE address is per-lane ----
__device__ __forceinline__ void stage16(const void* g, void* l) {
    __builtin_amdgcn_global_load_lds(
        (const __attribute__((address_space(1))) void*)g,
        (__attribute__((address_space(3))) void*)l, 16, 0, 0);
}

// ---- DPP wave-64 sum: result lands in lane 63 ----
template <int CTRL, int RMASK>
__device__ __forceinline__ float dpp_add_step(float x) {
    int v = __builtin_amdgcn_update_dpp(0, __float_as_int(x), CTRL, RMASK, 0xF, false);
    return x + __int_as_float(v);
}
__device__ __forceinline__ float wave_sum63(float x) {
    x = dpp_add_step<0x111, 0xF>(x);  // row_shr:1
    x = dpp_add_step<0x112, 0xF>(x);  // row_shr:2
    x = dpp_add_step<0x114, 0xF>(x);  // row_shr:4
    x = dpp_add_step<0x118, 0xF>(x);  // row_shr:8
    x = dpp_add_step<0x142, 0xA>(x);  // row_bcast:15 -> rows 1,3
    x = dpp_add_step<0x143, 0xC>(x);  // row_bcast:31 -> rows 2,3
    return x;                          // lane 63 = full sum
}

__device__ __forceinline__ float waveSumAll(float v) {
    for (int m = 32; m > 0; m >>= 1) v += __shfl_xor(v, m, 64);
    return v;
}

__device__ __forceinline__ float softplusf(float x) {
    return fmaxf(x, 0.f) + log1pf(__expf(-fabsf(x)));
}

// ---------------------------------------------------------------------------
// Fused kernel. Block regions:
//   [0, 1024)        dice: PER-WAVE autonomous double-buffered pipeline.
//                    Each wave stages its own 4-pixel tile (4 KB, 4 stage16),
//                    one counted vmcnt(4) per tile, lgkmcnt(0) before slot
//                    reuse. ZERO block barriers -> no 4-wave convoy.
//                    LDS = 4 waves * 2 slots * 4 KB = 32 KB -> 5 blocks/CU.
//   [1024, 1986)     small: +0 class, +1 nll, +2..385 bce 7x7, +386..961 occ CE
// ---------------------------------------------------------------------------
__global__ __launch_bounds__(256) void fused_kernel(
    const float* __restrict__ logit,    // [640]
    const float* __restrict__ trueseg,  // [B,H,W,E]
    const float* __restrict__ binlog,   // [B,H,W,Q]
    const float* __restrict__ por,      // [B,H,W,Q]
    const float* __restrict__ inc,      // [B,E,2]
    const float* __restrict__ pos,      // [B,Q,2]
    const float* __restrict__ chol,     // [B,Q,2,2]
    const float* __restrict__ occlog,   // [B,H,W,4]
    const int* __restrict__ occtrue,    // [B,H,W]
    const int* __restrict__ mqall,      // [B,M]
    const int* __restrict__ meall,      // [B,M]
    float* __restrict__ ws)
{
    __shared__ float tilebuf[4 * 2 * WTILE_B / 4];   // 32768 B exactly
    const int tid  = threadIdx.x;
    const int lane = tid & 63;
    const int wid  = tid >> 6;
    const int blk  = blockIdx.x;

    if (blk < NDICE) {
        // ================= dice: numerator + true-sum =================
        const int b = blk >> 8;            // 256 slots per batch
        const int slot = blk & 255;
        const bool hi = lane < 32;
        const int l31 = lane & 31;
        const int* mq = mqall + b * M_;
        const int* me = meall + b * M_;
        // unconditional index loads (64+l31 <= 95 in-bounds); second-half
        // contribution masked by m1 -> no exec divergence anywhere
        const int mqa = mq[lane];
        const int mea = me[lane];
        const int mqb = mq[64 + l31];
        const int meb = me[64 + l31];
        const float m1 = hi ? 1.f : 0.f;

        const char* porb = (const char*)(por + (size_t)b * HW_ * Q_);
        const char* trb  = (const char*)(trueseg + (size_t)b * HW_ * E_);

        // drain index loads: from here on, vmcnt counts ONLY tile stage loads
        asm volatile("s_waitcnt vmcnt(0)" ::: "memory");

        char* wbase = (char*)tilebuf + wid * (2 * WTILE_B);   // wave-private 8 KB

        float an = 0.f;   // numerator (valid on lane 63)
        float at = 0.f;   // true-sum partial (per-lane)

        // wave-tile t covers pixels (slot + t*256)*16 + wid*4 .. +4
        // LDS slot layout: [4 px][160 f] por then [4 px][96 f] true (4096 B)
        #define STAGE(t_) do {                                                 \
            const int p0_ = (slot + (t_) * 256) * 16 + wid * 4;                \
            const char* gp_ = porb + (size_t)p0_ * 640;                        \
            const char* gt_ = trb  + (size_t)p0_ * 384;                        \
            char* dst_ = wbase + ((t_) & 1) * WTILE_B;                         \
            _Pragma("unroll")                                                  \
            for (int i_ = 0; i_ < 4; ++i_) {                                   \
                const int off_ = i_ * 1024 + lane * 16;                        \
                const char* s_ = (off_ < 2560) ? (gp_ + off_)                  \
                                               : (gt_ + (off_ - 2560));        \
                stage16(s_, dst_ + i_ * 1024);                                 \
            }                                                                  \
        } while (0)

        #define COMP(t_) do {                                                  \
            const float* pl_ = (const float*)(wbase + ((t_) & 1) * WTILE_B);   \
            const float* tl_ = pl_ + 640;                                      \
            _Pragma("unroll")                                                  \
            for (int k_ = 0; k_ < 4; ++k_) {                                   \
                float p0v_ = pl_[k_ * Q_ + mqa];                               \
                float t0_  = tl_[k_ * E_ + mea];                               \
                float p1_  = pl_[k_ * Q_ + mqb];                               \
                float t1_  = tl_[k_ * E_ + meb];                               \
                float e0_ = __expf(p0v_);                                      \
                float e1_ = __expf(p1_) * m1;                                  \
                float s_  = wave_sum63(e0_ + e1_);                             \
                float se_ = wave_sum63(fmaf(t1_, e1_, t0_ * e0_));             \
                an += __fdividef(se_, s_);                                     \
                at += fmaf(t1_, m1, t0_);                                      \
            }                                                                  \
        } while (0)

        // prologue: 2 tiles in flight (8 loads)
        STAGE(0); STAGE(1);

        // steady state, per wave, NO barriers:
        //   invariant entering t: tiles {t, t+1} outstanding (8 loads)
        //   vmcnt(4) -> tile t landed (in-order retirement), t+1 still flying
        //   lgkmcnt(0) -> my ds_reads retired -> slot (t&1) reuse is WAR-safe
        for (int t = 0; t < NTILE - 2; ++t) {
            asm volatile("s_waitcnt vmcnt(4)" ::: "memory");
            COMP(t);
            asm volatile("s_waitcnt lgkmcnt(0)" ::: "memory");
            STAGE(t + 2);
        }
        // t = NTILE-2: tiles {7,8} outstanding -> wait tile 7
        asm volatile("s_waitcnt vmcnt(4)" ::: "memory");
        COMP(NTILE - 2);
        // t = NTILE-1: last tile
        asm volatile("s_waitcnt vmcnt(0)" ::: "memory");
        COMP(NTILE - 1);

        #undef STAGE
        #undef COMP

        // per-wave epilogue: no cross-wave reduce needed, atomics are cheap
        float atr = wave_sum63(at);
        if (lane == 63) {
            int bucket = blk & (NBUCKET - 1);
            atomicAdd(&ws[WS_NUM0 + bucket * 4 + b], 2.f * an);
            atomicAdd(&ws[WS_TS0  + bucket * 4 + b], atr);
        }
    } else {
        float* lab = tilebuf;            // alias: 640 floats
        const int s = blk - NDICE;
        float acc = 0.f;
        if (s == 0) {
            // ---- class loss ----
            for (int i = tid; i < B_ * Q_; i += 256) lab[i] = 0.f;
            __syncthreads();
            for (int i = tid; i < B_ * M_; i += 256) {
                int b = i / M_;
                lab[b * Q_ + mqall[i]] = 1.f;
            }
            __syncthreads();
            for (int i = tid; i < B_ * Q_; i += 256) {
                float x = logit[i];
                float z = lab[i];
                float w = z > 0.f ? 1.f : 0.1f;
                acc += w * (softplusf(x) - x * z);
            }
            float wsum = wave_sum63(acc);
            if (lane == 63) atomicAdd(&ws[0], wsum);
        } else if (s == 1) {
            // ---- distance NLL ----
            for (int i = tid; i < B_ * M_; i += 256) {
                int b = i / M_;
                int qi = mqall[i];
                int ei = meall[i];
                float px = inc[(b * E_ + ei) * 2 + 0];
                float py = inc[(b * E_ + ei) * 2 + 1];
                float cx = pos[(b * Q_ + qi) * 2 + 0];
                float cy = pos[(b * Q_ + qi) * 2 + 1];
                const float* ch = chol + (size_t)(b * Q_ + qi) * 4;
                float l00 = ch[0], l10 = ch[2], l11 = ch[3];
                float d0 = px - cx, d1 = py - cy;
                float z0 = d0 / l00;
                float z1 = (d1 - l10 * z0) / l11;
                float nll = 0.5f * (z0 * z0 + z1 * z1) + 1.837877066409345f
                            + logf(l00) + logf(l11);
                if (isinf(nll)) nll = 1e7f;
                acc += nll;
            }
            float wsum = wave_sum63(acc);
            if (lane == 63) atomicAdd(&ws[2], wsum);
        } else if (s < 386) {
            // ---- 7x7 window BCE, one block per (b, m); active threads in wave 0 ----
            int idx = s - 2;
            int b = idx / M_;
            int ei = meall[idx];
            int qi = mqall[idx];
            float px = inc[(b * E_ + ei) * 2 + 0];
            float py = inc[(b * E_ + ei) * 2 + 1];
            int r0 = (int)floorf(px) - 3;
            int c0 = (int)floorf(py) - 3;
            if (tid < 49) {
                int rr = r0 + tid / 7;
                int cc = c0 + tid % 7;
                size_t pix = ((size_t)b * H_ + rr) * W_ + cc;
                float tv = trueseg[pix * E_ + ei];
                float lg = binlog[pix * Q_ + qi];
                acc = softplusf(lg) - lg * tv;
            }
            if (wid == 0) {
                float wsum = wave_sum63(acc);
                if (lane == 63) atomicAdd(&ws[1], wsum);
            }
        } else {
            // ---- occupancy cross-entropy, 256 pixels per block ----
            int p = (s - 386) * 256 + tid;
            if (p < NPIX_) {
                float4 v = *(const float4*)(occlog + (size_t)p * 4);
                int lb = occtrue[p];
                float m = fmaxf(fmaxf(v.x, v.y), fmaxf(v.z, v.w));
                float lse = m + __logf(__expf(v.x - m) + __expf(v.y - m) +
                                       __expf(v.z - m) + __expf(v.w - m));
                float xs = lb == 0 ? v.x : (lb == 1 ? v.y : (lb == 2 ? v.z : v.w));
                acc = lse - xs;
            }
            float wsum = wave_sum63(acc);
            if (lane == 63) atomicAdd(&ws[3], wsum);
        }
    }
}

// ---------------------------------------------------------------------------
// Final combine: one wave. Lane k owns bucket k.
// ---------------------------------------------------------------------------
__global__ __launch_bounds__(64) void final_kernel(const float* __restrict__ ws,
                                                   float* __restrict__ out)
{
    const int lane = threadIdx.x;
    float n[B_], t[B_];
    for (int b = 0; b < B_; ++b) {
        n[b] = waveSumAll(ws[WS_NUM0 + lane * 4 + b]);
        t[b] = waveSumAll(ws[WS_TS0  + lane * 4 + b]);
    }
    if (lane == 0) {
        float class_l = ws[0] * (1.f / (B_ * Q_));
        float bce_l   = ws[1] * (1.f / (B_ * M_ * 49));
        float nll_l   = ws[2] * (1.f / (B_ * M_));
        float occ_l   = ws[3] * (1.f / NPIX_);
        float dice = 0.f;
        for (int b = 0; b < B_; ++b)
            dice += 1.f - (n[b] + 1.f) / (t[b] + (float)HW_ + 1.f);
        dice *= (1.f / B_);
        out[0] = class_l + bce_l + nll_l + occ_l + dice;
    }
}

extern "C" void kernel_launch(void* const* d_in, const int* in_sizes, int n_in,
                              void* d_out, int out_size, void* d_ws, size_t ws_size,
                              hipStream_t stream) {
    const float* logit   = (const float*)d_in[0];
    const float* trueseg = (const float*)d_in[1];
    const float* binlog  = (const float*)d_in[2];
    const float* por     = (const float*)d_in[3];
    const float* inc     = (const float*)d_in[4];
    const float* pos     = (const float*)d_in[5];
    const float* chol    = (const float*)d_in[6];
    const float* occlog  = (const float*)d_in[7];
    const int*   occtrue = (const int*)d_in[8];
    const int*   mq      = (const int*)d_in[9];
    const int*   me      = (const int*)d_in[10];
    float* out = (float*)d_out;
    float* ws  = (float*)d_ws;

    (void)hipMemsetAsync(d_ws, 0, WS_TOTAL * sizeof(float), stream);

    hipLaunchKernelGGL(fused_kernel, dim3(NDICE + NSMALL), dim3(256), 0, stream,
                       logit, trueseg, binlog, por, inc, pos, chol, occlog, occtrue,
                       mq, me, ws);
    hipLaunchKernelGGL(final_kernel, dim3(1), dim3(64), 0, stream, ws, out);
}

// Round 6
// 255.636 us; speedup vs baseline: 1.0283x; 1.0283x over previous
//
#include <hip/hip_runtime.h>
#include <math.h>

#define B_ 4
#define H_ 192
#define W_ 192
#define Q_ 160
#define E_ 96
#define M_ 96
#define HW_ (H_ * W_)          // 36864
#define NPIX_ (B_ * HW_)       // 147456
#define TPIX 16                // pixels per tile
#define NTILE 9                // 36864 / (256 slots * 16 px)
#define PORT_B (TPIX * Q_ * 4) // 10240 B por tile
#define NDICE 1024             // 256 slots per batch * 4 batches
#define NSMALL 962             // 2 + 384 + 576
#define NBUCKET 64
// ws layout (floats): [0]=class [1]=bce [2]=nll [3]=occ
//   [4   + k*4 + b] k<64 : dice numerator partials
//   [260 + k*4 + b] k<64 : sum_true partials
#define WS_NUM0 4
#define WS_TS0  260
#define WS_TOTAL 516

// ---- async global->LDS, 16 B per lane; lds dest = wave-uniform base + lane*16 ----
__device__ __forceinline__ void stage16(const void* g, void* l) {
    __builtin_amdgcn_global_load_lds(
        (const __attribute__((address_space(1))) void*)g,
        (__attribute__((address_space(3))) void*)l, 16, 0, 0);
}

// ---- DPP wave-64 sum: result lands in lane 63 ----
template <int CTRL, int RMASK>
__device__ __forceinline__ float dpp_add_step(float x) {
    int v = __builtin_amdgcn_update_dpp(0, __float_as_int(x), CTRL, RMASK, 0xF, false);
    return x + __int_as_float(v);
}
__device__ __forceinline__ float wave_sum63(float x) {
    x = dpp_add_step<0x111, 0xF>(x);  // row_shr:1
    x = dpp_add_step<0x112, 0xF>(x);  // row_shr:2
    x = dpp_add_step<0x114, 0xF>(x);  // row_shr:4
    x = dpp_add_step<0x118, 0xF>(x);  // row_shr:8
    x = dpp_add_step<0x142, 0xA>(x);  // row_bcast:15 -> rows 1,3
    x = dpp_add_step<0x143, 0xC>(x);  // row_bcast:31 -> rows 2,3
    return x;                          // lane 63 = full sum
}

__device__ __forceinline__ float waveSumAll(float v) {
    for (int m = 32; m > 0; m >>= 1) v += __shfl_xor(v, m, 64);
    return v;
}

__device__ __forceinline__ float softplusf(float x) {
    return fmaxf(x, 0.f) + log1pf(__expf(-fabsf(x)));
}

// ---------------------------------------------------------------------------
// Fused kernel. Dice path uses the pairq re-indexing:
//   se = sum_c true[pix][c] * exp(por[pix][pairq[c]]),  pairq[c]=mq[me^-1[c]]
//   -> true is CONTIGUOUS (register path, no LDS), only por is gathered.
//   LDS: 2 x 10 KB por tiles (+ 768 B tables) -> 7 blocks/CU.
//   Loop skeleton identical to the proven R0 schedule (stage-ahead + 1 sync).
// ---------------------------------------------------------------------------
__global__ __launch_bounds__(256) void fused_kernel(
    const float* __restrict__ logit,    // [640]
    const float* __restrict__ trueseg,  // [B,H,W,E]
    const float* __restrict__ binlog,   // [B,H,W,Q]
    const float* __restrict__ por,      // [B,H,W,Q]
    const float* __restrict__ inc,      // [B,E,2]
    const float* __restrict__ pos,      // [B,Q,2]
    const float* __restrict__ chol,     // [B,Q,2,2]
    const float* __restrict__ occlog,   // [B,H,W,4]
    const int* __restrict__ occtrue,    // [B,H,W]
    const int* __restrict__ mqall,      // [B,M]
    const int* __restrict__ meall,      // [B,M]
    float* __restrict__ ws)
{
    __shared__ float tilebuf[2 * TPIX * Q_];   // 20480 B: two por tiles
    __shared__ int   smq[M_];                  // 384 B
    __shared__ int   sinv[M_];                 // 384 B
    const int tid  = threadIdx.x;
    const int lane = tid & 63;
    const int wid  = tid >> 6;
    const int blk  = blockIdx.x;

    if (blk < NDICE) {
        // ================= dice: numerator + true-sum =================
        const int b = blk >> 8;            // 256 slots per batch
        const int slot = blk & 255;
        const bool hi = lane < 32;
        const int l31 = lane & 31;
        const int* mq = mqall + b * M_;
        const int* me = meall + b * M_;
        // build pairq tables: sinv[me[k]] = k, then pairq[c] = smq[sinv[c]]
        if (tid < M_) { smq[tid] = mq[tid]; sinv[me[tid]] = tid; }
        __syncthreads();
        const int pqa = smq[sinv[lane]];        // c = lane        (0..63)
        const int pqb = smq[sinv[64 + l31]];    // c = 64 + l31    (64..95)
        const float m1 = hi ? 1.f : 0.f;        // lanes >=32 duplicate c; mask

        const char* porb = (const char*)(por + (size_t)b * HW_ * Q_);
        const char* trb  = (const char*)(trueseg + (size_t)b * HW_ * E_);

        float an = 0.f;   // numerator (valid on lane 63)
        float at = 0.f;   // true-sum partial (per-lane)
        float tcur[8], tnxt[8];   // true regs: [k]=true[pix_k][lane], [4+k]=true[pix_k][64+l31]

        // por tile t -> buffer (t&1); 10 chunks of 1 KB, wave w takes chunks w,w+4,w+8
        #define STAGE(t_) do {                                                 \
            const int p0_ = (slot + (t_) * 256) * TPIX;                        \
            const char* gp_ = porb + (size_t)p0_ * 640;                        \
            char* db_ = (char*)tilebuf + ((t_) & 1) * PORT_B;                  \
            for (int i_ = wid; i_ < 10; i_ += 4)                               \
                stage16(gp_ + i_ * 1024 + lane * 16, db_ + i_ * 1024);         \
        } while (0)

        // true rows for this wave's 4 pixels -> registers (coalesced dwords)
        #define TLOAD(t_, dst_) do {                                           \
            const int p0_ = (slot + (t_) * 256) * TPIX + wid * 4;              \
            const char* gt_ = trb + (size_t)p0_ * 384;                         \
            _Pragma("unroll")                                                  \
            for (int k_ = 0; k_ < 4; ++k_) {                                   \
                dst_[k_]     = *(const float*)(gt_ + k_ * 384 + lane * 4);     \
                dst_[4 + k_] = *(const float*)(gt_ + k_ * 384 + 256 + l31 * 4);\
            }                                                                  \
        } while (0)

        #define COMP(t_, tc_) do {                                             \
            const float* pl_ = tilebuf + ((t_) & 1) * (TPIX * Q_);             \
            _Pragma("unroll")                                                  \
            for (int k_ = 0; k_ < 4; ++k_) {                                   \
                const int pix_ = wid * 4 + k_;                                 \
                float e0_ = __expf(pl_[pix_ * Q_ + pqa]);                      \
                float e1_ = __expf(pl_[pix_ * Q_ + pqb]) * m1;                 \
                float t0_ = tc_[k_];                                           \
                float t1_ = tc_[4 + k_] * m1;                                  \
                float s_  = wave_sum63(e0_ + e1_);                             \
                float se_ = wave_sum63(fmaf(t1_, e1_, t0_ * e0_));             \
                an += __fdividef(se_, s_);                                     \
                at += t0_ + t1_;                                               \
            }                                                                  \
        } while (0)

        // prologue: tile 0 in flight
        STAGE(0);
        TLOAD(0, tcur);

        // 2x-unrolled R0 schedule: sync (drains tile t + its true regs),
        // issue tile t+1, compute tile t. Static reg-buffer roles via parity.
        for (int tt = 0; tt < 4; ++tt) {
            const int t = 2 * tt;
            __syncthreads();                 // tile t (buf t&1) + tcur ready
            STAGE(t + 1);                    // -> buf1-parity; safe: prev COMP done
            TLOAD(t + 1, tnxt);
            COMP(t, tcur);
            __syncthreads();                 // tile t+1 + tnxt ready
            STAGE(t + 2);                    // t+2 <= 8 always
            TLOAD(t + 2, tcur);
            COMP(t + 1, tnxt);
        }
        __syncthreads();                     // tile 8 + tcur ready
        COMP(8, tcur);

        #undef STAGE
        #undef TLOAD
        #undef COMP

        // per-wave epilogue: order-free atomic partials
        float atr = wave_sum63(at);
        if (lane == 63) {
            int bucket = blk & (NBUCKET - 1);
            atomicAdd(&ws[WS_NUM0 + bucket * 4 + b], 2.f * an);
            atomicAdd(&ws[WS_TS0  + bucket * 4 + b], atr);
        }
    } else {
        float* lab = tilebuf;            // alias: 640 floats
        const int s = blk - NDICE;
        float acc = 0.f;
        if (s == 0) {
            // ---- class loss ----
            for (int i = tid; i < B_ * Q_; i += 256) lab[i] = 0.f;
            __syncthreads();
            for (int i = tid; i < B_ * M_; i += 256) {
                int b = i / M_;
                lab[b * Q_ + mqall[i]] = 1.f;
            }
            __syncthreads();
            for (int i = tid; i < B_ * Q_; i += 256) {
                float x = logit[i];
                float z = lab[i];
                float w = z > 0.f ? 1.f : 0.1f;
                acc += w * (softplusf(x) - x * z);
            }
            float wsum = wave_sum63(acc);
            if (lane == 63) atomicAdd(&ws[0], wsum);
        } else if (s == 1) {
            // ---- distance NLL ----
            for (int i = tid; i < B_ * M_; i += 256) {
                int b = i / M_;
                int qi = mqall[i];
                int ei = meall[i];
                float px = inc[(b * E_ + ei) * 2 + 0];
                float py = inc[(b * E_ + ei) * 2 + 1];
                float cx = pos[(b * Q_ + qi) * 2 + 0];
                float cy = pos[(b * Q_ + qi) * 2 + 1];
                const float* ch = chol + (size_t)(b * Q_ + qi) * 4;
                float l00 = ch[0], l10 = ch[2], l11 = ch[3];
                float d0 = px - cx, d1 = py - cy;
                float z0 = d0 / l00;
                float z1 = (d1 - l10 * z0) / l11;
                float nll = 0.5f * (z0 * z0 + z1 * z1) + 1.837877066409345f
                            + logf(l00) + logf(l11);
                if (isinf(nll)) nll = 1e7f;
                acc += nll;
            }
            float wsum = wave_sum63(acc);
            if (lane == 63) atomicAdd(&ws[2], wsum);
        } else if (s < 386) {
            // ---- 7x7 window BCE, one block per (b, m); active threads in wave 0 ----
            int idx = s - 2;
            int b = idx / M_;
            int ei = meall[idx];
            int qi = mqall[idx];
            float px = inc[(b * E_ + ei) * 2 + 0];
            float py = inc[(b * E_ + ei) * 2 + 1];
            int r0 = (int)floorf(px) - 3;
            int c0 = (int)floorf(py) - 3;
            if (tid < 49) {
                int rr = r0 + tid / 7;
                int cc = c0 + tid % 7;
                size_t pix = ((size_t)b * H_ + rr) * W_ + cc;
                float tv = trueseg[pix * E_ + ei];
                float lg = binlog[pix * Q_ + qi];
                acc = softplusf(lg) - lg * tv;
            }
            if (wid == 0) {
                float wsum = wave_sum63(acc);
                if (lane == 63) atomicAdd(&ws[1], wsum);
            }
        } else {
            // ---- occupancy cross-entropy, 256 pixels per block ----
            int p = (s - 386) * 256 + tid;
            if (p < NPIX_) {
                float4 v = *(const float4*)(occlog + (size_t)p * 4);
                int lb = occtrue[p];
                float m = fmaxf(fmaxf(v.x, v.y), fmaxf(v.z, v.w));
                float lse = m + __logf(__expf(v.x - m) + __expf(v.y - m) +
                                       __expf(v.z - m) + __expf(v.w - m));
                float xs = lb == 0 ? v.x : (lb == 1 ? v.y : (lb == 2 ? v.z : v.w));
                acc = lse - xs;
            }
            float wsum = wave_sum63(acc);
            if (lane == 63) atomicAdd(&ws[3], wsum);
        }
    }
}

// ---------------------------------------------------------------------------
// Final combine: one wave. Lane k owns bucket k.
// ---------------------------------------------------------------------------
__global__ __launch_bounds__(64) void final_kernel(const float* __restrict__ ws,
                                                   float* __restrict__ out)
{
    const int lane = threadIdx.x;
    float n[B_], t[B_];
    for (int b = 0; b < B_; ++b) {
        n[b] = waveSumAll(ws[WS_NUM0 + lane * 4 + b]);
        t[b] = waveSumAll(ws[WS_TS0  + lane * 4 + b]);
    }
    if (lane == 0) {
        float class_l = ws[0] * (1.f / (B_ * Q_));
        float bce_l   = ws[1] * (1.f / (B_ * M_ * 49));
        float nll_l   = ws[2] * (1.f / (B_ * M_));
        float occ_l   = ws[3] * (1.f / NPIX_);
        float dice = 0.f;
        for (int b = 0; b < B_; ++b)
            dice += 1.f - (n[b] + 1.f) / (t[b] + (float)HW_ + 1.f);
        dice *= (1.f / B_);
        out[0] = class_l + bce_l + nll_l + occ_l + dice;
    }
}

extern "C" void kernel_launch(void* const* d_in, const int* in_sizes, int n_in,
                              void* d_out, int out_size, void* d_ws, size_t ws_size,
                              hipStream_t stream) {
    const float* logit   = (const float*)d_in[0];
    const float* trueseg = (const float*)d_in[1];
    const float* binlog  = (const float*)d_in[2];
    const float* por     = (const float*)d_in[3];
    const float* inc     = (const float*)d_in[4];
    const float* pos     = (const float*)d_in[5];
    const float* chol    = (const float*)d_in[6];
    const float* occlog  = (const float*)d_in[7];
    const int*   occtrue = (const int*)d_in[8];
    const int*   mq      = (const int*)d_in[9];
    const int*   me      = (const int*)d_in[10];
    float* out = (float*)d_out;
    float* ws  = (float*)d_ws;

    (void)hipMemsetAsync(d_ws, 0, WS_TOTAL * sizeof(float), stream);

    hipLaunchKernelGGL(fused_kernel, dim3(NDICE + NSMALL), dim3(256), 0, stream,
                       logit, trueseg, binlog, por, inc, pos, chol, occlog, occtrue,
                       mq, me, ws);
    hipLaunchKernelGGL(final_kernel, dim3(1), dim3(64), 0, stream, ws, out);
}